// Round 10
// baseline (315.135 us; speedup 1.0000x reference)
//
#include <hip/hip_runtime.h>
#include <cstdint>
#include <cstddef>

#define NN 30000
#define NE 480000
#define NG 128
#define DIN 128
#define DH 256
#define NC 60
#define CAP 64               // bucket capacity per node (true deg ~ Poisson(16); P(>64) ~ 1e-20)
#define P1MAX (NN * DIN / 4) // 960000: widest job in pre phase

typedef _Float16 f16x8 __attribute__((ext_vector_type(8)));
typedef _Float16 half4_t __attribute__((ext_vector_type(4)));
typedef float f32x4 __attribute__((ext_vector_type(4)));

// ---------------- fused pre: bucket edges + x->fp16 + W->fp16 + zero sums ----------------
__global__ __launch_bounds__(256) void k_pre(const int* __restrict__ ei, int* __restrict__ cursor,
        int* __restrict__ csr_src,
        const float* __restrict__ x, _Float16* __restrict__ xh,
        const float* __restrict__ W1, const float* __restrict__ W2, const float* __restrict__ W3,
        _Float16* __restrict__ w1h, _Float16* __restrict__ w2h, _Float16* __restrict__ w3h,
        float* __restrict__ sums) {
    int i = blockIdx.x * 256 + threadIdx.x;
    if (i < NE) {
        int s = ei[i];        // edge_index[0]
        int d = ei[NE + i];   // edge_index[1]
        int slot = atomicAdd(&cursor[d], 1);
        if (slot < CAP) csr_src[d * CAP + slot] = s;
    }
    if (i < P1MAX) {
        float4 v = ((const float4*)x)[i];
        half4_t o;
        o[0] = (_Float16)v.x; o[1] = (_Float16)v.y;
        o[2] = (_Float16)v.z; o[3] = (_Float16)v.w;
        ((half4_t*)xh)[i] = o;
    }
    if (i < DH * DIN) w1h[i] = (_Float16)W1[i];
    if (i < DH * DH) {
        w2h[i] = (_Float16)W2[i];
        w3h[i] = (_Float16)W3[i];
    }
    if (i < NG * DH) sums[i] = 0.f;
}

// ---------------- aggregation: u[v] = sum_e w_e*hin[src_e] + hin[v]/(deg_v+1) ----------------
// Measured-best structure (r2 profile: 44.3us), restored after three failed attacks
// (r3/r5 slicing: overhead dup; r9 sub-wave ILP: 47.5us). Treated as the agg floor.
// One wave per node. 16B/lane gathers: wave splits into G = 64/(K/8) lane-groups, each
// group owns one edge of the current batch. Tier 16 keeps 8 (K=256) / 4 (K=128) row
// gathers in flight per lane; predicated 8-edge rounds for the tail.
// Cross-group butterfly reduce at the end. fp16 plane in/out, fp32 accumulate.
template<int K>
__global__ __launch_bounds__(256) void k_agg(const _Float16* __restrict__ hin,
        _Float16* __restrict__ tout, const int* __restrict__ cnt,
        const int* __restrict__ csr_src) {
    constexpr int L = K / 8;   // lanes per row (16B chunks per row)
    constexpr int G = 64 / L;  // edges per wave round (2 for K=256, 4 for K=128)
    constexpr int B16 = 16 / G;
    constexpr int B8 = 8 / G;
    int node = blockIdx.x * 4 + (threadIdx.x >> 6);
    int lane = threadIdx.x & 63;
    int sub = lane / L;        // edge slot within the round
    int off = lane % L;        // 8-half chunk index within the row
    const _Float16* gbase = hin + off * 8;
    float acc[8];
    #pragma unroll
    for (int u = 0; u < 8; u++) acc[u] = 0.f;
    int deg = cnt[node];
    float dvd = rsqrtf((float)(deg + 1));
    int c = deg < CAP ? deg : CAP;
    int beg = node * CAP, end = beg + c;
    int e = beg;
    // tier 16: covers a whole typical (deg~16) node in one batch
    for (; e + 16 <= end; e += 16) {
        int s[B16]; float w[B16]; f16x8 r[B16];
        #pragma unroll
        for (int j = 0; j < B16; j++) s[j] = csr_src[e + j * G + sub];
        #pragma unroll
        for (int j = 0; j < B16; j++) r[j] = *(const f16x8*)(gbase + (size_t)s[j] * K);
        #pragma unroll
        for (int j = 0; j < B16; j++) w[j] = rsqrtf((float)(cnt[s[j]] + 1)) * dvd;
        #pragma unroll
        for (int j = 0; j < B16; j++)
            #pragma unroll
            for (int u = 0; u < 8; u++) acc[u] = fmaf(w[j], (float)r[j][u], acc[u]);
    }
    // predicated 8-edge rounds (<=2): idle lanes get weight 0 on a safe (self) row
    for (; e < end; e += 8) {
        int s[B8]; float w[B8]; f16x8 r[B8];
        #pragma unroll
        for (int j = 0; j < B8; j++) {
            int idx = e + j * G + sub;
            s[j] = (idx < end) ? csr_src[idx] : node;
        }
        #pragma unroll
        for (int j = 0; j < B8; j++)
            r[j] = *(const f16x8*)(gbase + (size_t)s[j] * K);
        #pragma unroll
        for (int j = 0; j < B8; j++) {
            int idx = e + j * G + sub;
            w[j] = (idx < end) ? rsqrtf((float)(cnt[s[j]] + 1)) * dvd : 0.f;
        }
        #pragma unroll
        for (int j = 0; j < B8; j++)
            #pragma unroll
            for (int u = 0; u < 8; u++) acc[u] = fmaf(w[j], (float)r[j][u], acc[u]);
    }
    // self loop: weight 1/(deg+1), counted once (only sub==0 lanes add it)
    {
        float sws = (sub == 0) ? dvd * dvd : 0.f;
        f16x8 rs = *(const f16x8*)(gbase + (size_t)node * K);
        #pragma unroll
        for (int u = 0; u < 8; u++) acc[u] = fmaf(sws, (float)rs[u], acc[u]);
    }
    // butterfly reduce across edge slots (partners share 'off' since L | mask)
    #pragma unroll
    for (int u = 0; u < 8; u++) {
        float v = acc[u];
        #pragma unroll
        for (int m = L; m < 64; m <<= 1) v += __shfl_xor(v, m, 64);
        acc[u] = v;
    }
    if (sub == 0) {
        f16x8 o;
        #pragma unroll
        for (int u = 0; u < 8; u++) o[u] = (_Float16)acc[u];
        *(f16x8*)(tout + (size_t)node * K + off * 8) = o;
    }
}

// ---------------- fp16 MFMA GEMM: C[M x 256] = relu(A * W^T + bias) ----------------
// Direct-from-L2 register GEMM (this round's change): NO LDS, NO barriers.
// Rationale: r7 (-22us) showed staging coalescing dominates; r8 (neutral) showed barrier
// count/epilogue don't matter -> the residual cost is the LDS round-trip + the forced
// vmcnt(0)-at-barrier drain itself. Here each lane loads its MFMA fragments directly:
// per k-step a wave issues 4 dwordx4 (16 rows x 64B contiguous, fully-used lines) + 4
// MFMA, fully unrolled -> compiler pipelines loads across k-steps with no sync points.
// W is 128 KB (L2-hot in every XCD); A rows are read <=4x from L2/LLC streams.
// Wave tile 32x32 (2x2 of 16x16x32), 4 waves/block, grid (469,4) = 7.3 blocks/CU;
// launch_bounds(256,4) caps VGPR at 128 (>=4 waves/SIMD).
// FUSE_POOL=true (layer 3): epilogue run-sums per graph (batch sorted) -> atomicAdd.
template<int K, bool FUSE_POOL>
__global__ __launch_bounds__(256, 4) void k_gemm(const _Float16* __restrict__ A,
        const _Float16* __restrict__ W, const float* __restrict__ bias,
        _Float16* __restrict__ Cb, const int* __restrict__ batch,
        float* __restrict__ sums) {
    int t = threadIdx.x;
    int bm = blockIdx.x * 64;
    int bn = blockIdx.y * 64;
    int lane = t & 63, wv = t >> 6;
    int wm = (wv & 1) * 32;
    int wn = (wv >> 1) * 32;
    int lm = lane & 15, q = lane >> 4;
    int ra0 = bm + wm + lm;      if (ra0 >= NN) ra0 = NN - 1;
    int ra1 = bm + wm + 16 + lm; if (ra1 >= NN) ra1 = NN - 1;
    const _Float16* pa0 = A + (size_t)ra0 * K + q * 8;
    const _Float16* pa1 = A + (size_t)ra1 * K + q * 8;
    const _Float16* pb0 = W + (size_t)(bn + wn + lm) * K + q * 8;
    const _Float16* pb1 = W + (size_t)(bn + wn + 16 + lm) * K + q * 8;

    f32x4 acc[2][2];
    #pragma unroll
    for (int i = 0; i < 2; i++)
        #pragma unroll
        for (int j = 0; j < 2; j++) acc[i][j] = (f32x4){0.f, 0.f, 0.f, 0.f};

    #pragma unroll
    for (int k0 = 0; k0 < K; k0 += 32) {
        f16x8 a0 = *(const f16x8*)(pa0 + k0);
        f16x8 a1 = *(const f16x8*)(pa1 + k0);
        f16x8 b0 = *(const f16x8*)(pb0 + k0);
        f16x8 b1 = *(const f16x8*)(pb1 + k0);
        acc[0][0] = __builtin_amdgcn_mfma_f32_16x16x32_f16(a0, b0, acc[0][0], 0, 0, 0);
        acc[0][1] = __builtin_amdgcn_mfma_f32_16x16x32_f16(a0, b1, acc[0][1], 0, 0, 0);
        acc[1][0] = __builtin_amdgcn_mfma_f32_16x16x32_f16(a1, b0, acc[1][0], 0, 0, 0);
        acc[1][1] = __builtin_amdgcn_mfma_f32_16x16x32_f16(a1, b1, acc[1][1], 0, 0, 0);
    }
    // epilogue: C/D layout col = lane&15, row = q*4 + r
    if constexpr (!FUSE_POOL) {
        #pragma unroll
        for (int mt = 0; mt < 2; mt++) {
            #pragma unroll
            for (int nt = 0; nt < 2; nt++) {
                int col = bn + wn + nt * 16 + lm;
                float bv = bias[col];
                #pragma unroll
                for (int r = 0; r < 4; r++) {
                    int row = bm + wm + mt * 16 + q * 4 + r;
                    if (row < NN) {
                        float v = fmaxf(acc[mt][nt][r] + bv, 0.f);
                        Cb[(size_t)row * 256 + col] = (_Float16)v;
                    }
                }
            }
        }
    } else {
        // graph ids for this lane's 8 rows (ascending; reused across nt)
        int gid[8];
        #pragma unroll
        for (int mt = 0; mt < 2; mt++)
            #pragma unroll
            for (int r = 0; r < 4; r++) {
                int row = bm + wm + mt * 16 + q * 4 + r;
                gid[mt * 4 + r] = (row < NN) ? batch[row] : -1;
            }
        #pragma unroll
        for (int nt = 0; nt < 2; nt++) {
            int col = bn + wn + nt * 16 + lm;
            float bv = bias[col];
            float runsum = 0.f;
            int curg = -1;
            #pragma unroll
            for (int mt = 0; mt < 2; mt++) {
                #pragma unroll
                for (int r = 0; r < 4; r++) {
                    int g = gid[mt * 4 + r];
                    if (g >= 0) {
                        float v = fmaxf(acc[mt][nt][r] + bv, 0.f);
                        if (g != curg) {
                            if (curg >= 0) atomicAdd(&sums[curg * DH + col], runsum);
                            curg = g;
                            runsum = 0.f;
                        }
                        runsum += v;
                    }
                }
            }
            if (curg >= 0) atomicAdd(&sums[curg * DH + col], runsum);
        }
    }
}

// ---------------- FC: out[G x 60] = (sums[g]/cnt) @ Wfc[60 x 256]^T + bfc ----------------
__global__ __launch_bounds__(64) void k_fc(const float* __restrict__ sums,
        const int* __restrict__ batch, const float* __restrict__ Wfc,
        const float* __restrict__ bfc, float* __restrict__ out) {
    __shared__ float p[DH];
    int g = blockIdx.x;
    int t = threadIdx.x;
    int lo = 0, hi = NN;
    while (lo < hi) { int mid = (lo + hi) >> 1; if (batch[mid] < g) lo = mid + 1; else hi = mid; }
    int start = lo;
    hi = NN;
    while (lo < hi) { int mid = (lo + hi) >> 1; if (batch[mid] < g + 1) lo = mid + 1; else hi = mid; }
    int cnt = lo - start;
    float inv = (cnt > 0) ? 1.f / (float)cnt : 0.f;
    for (int i = t; i < DH; i += 64) p[i] = sums[g * DH + i] * inv;
    __syncthreads();
    if (t < NC) {
        float a = bfc[t];
        for (int k = 0; k < DH; k++) a = fmaf(p[k], Wfc[t * DH + k], a);
        out[g * NC + t] = a;
    }
}

extern "C" void kernel_launch(void* const* d_in, const int* in_sizes, int n_in,
                              void* d_out, int out_size, void* d_ws, size_t ws_size,
                              hipStream_t stream) {
    const float* x     = (const float*)d_in[0];
    const int*   ei    = (const int*)d_in[1];
    const int*   batch = (const int*)d_in[2];
    const float* W1 = (const float*)d_in[3];
    const float* b1 = (const float*)d_in[4];
    const float* W2 = (const float*)d_in[5];
    const float* b2 = (const float*)d_in[6];
    const float* W3 = (const float*)d_in[7];
    const float* b3 = (const float*)d_in[8];
    const float* Wfc = (const float*)d_in[9];
    const float* bfc = (const float*)d_in[10];
    float* out = (float*)d_out;

    char* wp = (char*)d_ws;
    auto alloc = [&](size_t bytes) {
        char* q = wp;
        wp += (bytes + 511) & ~(size_t)511;
        return (void*)q;
    };
    int*   cursor  = (int*)alloc((size_t)NN * 4);               // true in-degree after pre
    int*   csr_src = (int*)alloc((size_t)NN * CAP * 4);         // bucket CSR
    float* sums    = (float*)alloc((size_t)NG * DH * 4);        // zeroed inside k_pre
    _Float16* xh   = (_Float16*)alloc((size_t)NN * DIN * 2);
    _Float16* tb   = (_Float16*)alloc((size_t)NN * DH * 2);
    _Float16* hA   = (_Float16*)alloc((size_t)NN * DH * 2);
    _Float16* hB   = (_Float16*)alloc((size_t)NN * DH * 2);
    _Float16* w1h = (_Float16*)alloc((size_t)DH * DIN * 2);
    _Float16* w2h = (_Float16*)alloc((size_t)DH * DH * 2);
    _Float16* w3h = (_Float16*)alloc((size_t)DH * DH * 2);

    // only cursor must be zero before pre's atomics (120 KB)
    hipMemsetAsync(cursor, 0, (size_t)NN * 4, stream);

    k_pre<<<(P1MAX + 255) / 256, 256, 0, stream>>>(ei, cursor, csr_src, x, xh,
                                                   W1, W2, W3, w1h, w2h, w3h, sums);

    dim3 gg((NN + 63) / 64, 4);
    // h_l = relu((A.h_{l-1}) W^T + b)  [linearity reorder]
    k_agg<128><<<NN / 4, 256, 0, stream>>>(xh, tb, cursor, csr_src);
    k_gemm<128, false><<<gg, 256, 0, stream>>>(tb, w1h, b1, hA, nullptr, nullptr);
    k_agg<256><<<NN / 4, 256, 0, stream>>>(hA, tb, cursor, csr_src);
    k_gemm<256, false><<<gg, 256, 0, stream>>>(tb, w2h, b2, hB, nullptr, nullptr);
    k_agg<256><<<NN / 4, 256, 0, stream>>>(hB, tb, cursor, csr_src);
    k_gemm<256, true><<<gg, 256, 0, stream>>>(tb, w3h, b3, nullptr, batch, sums);  // + pool

    k_fc<<<NG, 64, 0, stream>>>(sums, batch, Wfc, bfc, out);
}